// Round 15
// baseline (520.390 us; speedup 1.0000x reference)
//
#include <hip/hip_runtime.h>

#define NPTS   262144
#define NBALLS 8192
#define MSZ    32

typedef unsigned short u16;
typedef __attribute__((ext_vector_type(8))) unsigned short u16x8;
typedef __attribute__((ext_vector_type(8))) __bf16 bf16x8;
typedef __attribute__((ext_vector_type(4))) float f32x4;
typedef __attribute__((ext_vector_type(2))) unsigned u32x2;

__device__ inline u16 f2bf(float f) {
    unsigned u = __builtin_bit_cast(unsigned, f);
    u += 0x7fffu + ((u >> 16) & 1u);           // RNE
    return (u16)(u >> 16);
}

__device__ inline unsigned pk2(float lo, float hi) {   // lo -> bits 0-15
    return (unsigned)f2bf(lo) | ((unsigned)f2bf(hi) << 16);
}

__device__ inline f32x4 mfma16(u16x8 a, u16x8 b, f32x4 c) {
    return __builtin_amdgcn_mfma_f32_16x16x32_bf16(
        __builtin_bit_cast(bf16x8, a), __builtin_bit_cast(bf16x8, b), c, 0, 0, 0);
}

__device__ inline void gload_lds16(const u16* g, u16* l) {
    __builtin_amdgcn_global_load_lds(
        (const __attribute__((address_space(1))) void*)g,
        (__attribute__((address_space(3))) void*)l, 16, 0, 0);
}

// ---------------- K0: weight prep — HEAD-MAJOR qkv transpose -----------------
// col2 = h*96 + mat*32 + e  <->  orig col = h*96 + e*3 + mat
// wqkvT2[col2*256 + k];  wpF unchanged (round-7 verified)
__global__ __launch_bounds__(256) void k0_wprep(const float* __restrict__ w_qkv,
                                                const float* __restrict__ b_qkv,
                                                const float* __restrict__ w_proj,
                                                u16* __restrict__ wqkvT2,
                                                u16* __restrict__ wpF,
                                                float* __restrict__ bq2) {
    int idx = blockIdx.x * 256 + threadIdx.x;
    if (idx < 768 * 256) {
        int cp = idx >> 8, r = idx & 255;
        int h = cp / 96, rem = cp % 96, mat = rem >> 5, e = rem & 31;
        int orig = h * 96 + e * 3 + mat;
        wqkvT2[cp * 256 + r] = f2bf(w_qkv[r * 768 + orig]);
        if (r == 0) bq2[cp] = b_qkv[orig];
    } else {
        int tid2 = idx - 768 * 256;             // < 8192 (grid = 800 blocks)
        int lane = tid2 & 63, ch = tid2 >> 6;
        int hk = ch & 7, gct = ch >> 3;
        int r15 = lane & 15, g4 = lane >> 4;
        u16x8 o;
#pragma unroll
        for (int j = 0; j < 8; ++j)
            o[j] = f2bf(w_proj[(size_t)(hk * 32 + g4 * 8 + j) * 256 + gct * 16 + r15]);
        *(u16x8*)&wpF[(size_t)tid2 * 8] = o;
    }
}

// ---------------- K1: fused pos-embed + QKV GEMM + attention ----------------
// 512 thr, 4 balls (128 rows). 8 head-chunks of 96 cols. Per head: GEMM ->
// qkvh LDS -> attention (k23 verbatim math) -> ao (bf16, [N][256]).
__global__ __launch_bounds__(512, 4) void k1_fused(const float* __restrict__ x,
                                                   const float* __restrict__ pos,
                                                   const float* __restrict__ w_pe,
                                                   const float* __restrict__ b_pe,
                                                   const u16* __restrict__ wqkvT2,
                                                   const float* __restrict__ bq2,
                                                   const float* __restrict__ sigma,
                                                   u16* __restrict__ ao) {
    __shared__ __align__(16) u16 Bs2[2][96 * 64];      // 24 KB dbuf
    __shared__ __align__(16) u16 qkvh[4][3][MSZ][32];  // 24 KB (also Astage in prologue)
    __shared__ float dist_s[4][MSZ][32];               // 16 KB
    __shared__ __align__(16) char upool[10240];        // prologue tables / P_s

    float* ps_s  = (float*)upool;            // 384
    float* ctr_s = ps_s + 384;               // 12
    float* rel_s = ctr_s + 12;               // 384  rel_s[row*3+d]
    float* wpe_s = rel_s + 384;               // 768  wpe_s[d*256+k]
    float* bpe_s = wpe_s + 768;               // 256
    typedef u16 (*PsT)[MSZ][40];
    PsT P_s = (PsT)upool;                     // P_s[4][32][40] (post-prologue)

    int id = blockIdx.x;
    int rt = (id >> 3) + (id & 7) * 256;      // bijective XCD swizzle (2048%8==0)
    int t = threadIdx.x;
    int lane = t & 63, wv = t >> 6;
    int r15 = lane & 15, g4 = lane >> 4;
    int wr = wv >> 1, wc = wv & 1;            // ball-in-block, col-half
    int rowbase = rt * 128;
    const int ball_g = rt * 4 + wr;
    const float scale = 0.17677669529663687f; // 1/sqrt(32)

    // ---- prologue tables + stage (hd0,kt0) ----
    if (t < 384) ps_s[t] = pos[(size_t)rt * 384 + t];
    if (t < 256) bpe_s[t] = b_pe[t];
    for (int i = t; i < 768; i += 512) wpe_s[i] = w_pe[i];
    {
        int c = t, row = c >> 3, sg = c & 7;
        gload_lds16(&wqkvT2[(size_t)row * 256 + (sg ^ (row & 7)) * 8], &Bs2[0][c * 8]);
        if (t < 256) {
            int c2 = 512 + t, row2 = c2 >> 3, sg2 = c2 & 7;
            gload_lds16(&wqkvT2[(size_t)row2 * 256 + (sg2 ^ (row2 & 7)) * 8], &Bs2[0][c2 * 8]);
        }
    }
    __syncthreads();
    if (t < 12) {
        int b = t / 3, m = t % 3;
        float s = 0.f;
#pragma unroll
        for (int j = 0; j < MSZ; ++j) s += ps_s[(b * 32 + j) * 3 + m];
        ctr_s[b * 3 + m] = s * (1.0f / MSZ);
    }
    __syncthreads();
    if (t < 384) {
        int p = t / 3, m = t % 3;
        rel_s[t] = ps_s[t] - ctr_s[(p >> 5) * 3 + m];
    }
    for (int idx2 = t; idx2 < 4096; idx2 += 512) {
        int b = idx2 >> 10, m = (idx2 >> 5) & 31, kk = idx2 & 31;
        float dx = ps_s[(b * 32 + m) * 3 + 0] - ps_s[(b * 32 + kk) * 3 + 0];
        float dy = ps_s[(b * 32 + m) * 3 + 1] - ps_s[(b * 32 + kk) * 3 + 1];
        float dz = ps_s[(b * 32 + m) * 3 + 2] - ps_s[(b * 32 + kk) * 3 + 2];
        dist_s[b][m][kk] = sqrtf(fmaxf(dx * dx + dy * dy + dz * dz, 1e-12f));
    }
    __syncthreads();                          // rel_s + dist ready

    // ---- embed -> register A-frags via qkvh as staging (R14 math verbatim) --
    u16* Ast = &qkvh[0][0][0][0];
    u16x8 af[2][8];
#pragma unroll
    for (int kt = 0; kt < 4; ++kt) {
#pragma unroll
        for (int i = 0; i < 2; ++i) {
            int c = i * 512 + t;
            int row = c >> 3, g = c & 7;
            int kk0 = kt * 64 + g * 8;
            float4 xa = *(const float4*)&x[(size_t)(rowbase + row) * 256 + kk0];
            float4 xb = *(const float4*)&x[(size_t)(rowbase + row) * 256 + kk0 + 4];
            float r0 = rel_s[row * 3 + 0], r1 = rel_s[row * 3 + 1], r2 = rel_s[row * 3 + 2];
            u16x8 o;
#pragma unroll
            for (int m = 0; m < 8; ++m) {
                float xv = (m < 4) ? ((const float*)&xa)[m] : ((const float*)&xb)[m - 4];
                float v = fmaf(r0, wpe_s[0 * 256 + kk0 + m],
                          fmaf(r1, wpe_s[1 * 256 + kk0 + m],
                          fmaf(r2, wpe_s[2 * 256 + kk0 + m], xv))) + bpe_s[kk0 + m];
                o[m] = f2bf(v);
            }
            *(u16x8*)&Ast[(row * 8 + (g ^ (row & 7))) * 8] = o;
        }
        __syncthreads();
#pragma unroll
        for (int ks = 0; ks < 2; ++ks)
#pragma unroll
            for (int i = 0; i < 2; ++i) {
                int R = wr * 32 + i * 16 + r15;
                af[i][2 * kt + ks] =
                    *(const u16x8*)&Ast[R * 64 + (((ks * 4 + g4) ^ (R & 7)) * 8)];
            }
        __syncthreads();
    }

    // ---- main loop: 8 heads × 4 kt ----
    f32x4 acc[3][2];
#pragma unroll
    for (int j = 0; j < 3; ++j)
#pragma unroll
        for (int i = 0; i < 2; ++i) acc[j][i] = (f32x4){0.f, 0.f, 0.f, 0.f};

    for (int hd = 0; hd < 8; ++hd) {
#pragma unroll
        for (int kt = 0; kt < 4; ++kt) {
            int cur = kt & 1;
            if (hd * 4 + kt < 31) {
                int nhd = (kt == 3) ? hd + 1 : hd;
                int nkt = (kt + 1) & 3;
                int c = t, row = c >> 3, sg = c & 7;
                gload_lds16(&wqkvT2[(size_t)(nhd * 96 + row) * 256 + nkt * 64 + (sg ^ (row & 7)) * 8],
                            &Bs2[cur ^ 1][c * 8]);
                if (t < 256) {
                    int c2 = 512 + t, row2 = c2 >> 3, sg2 = c2 & 7;
                    gload_lds16(&wqkvT2[(size_t)(nhd * 96 + row2) * 256 + nkt * 64 + (sg2 ^ (row2 & 7)) * 8],
                                &Bs2[cur ^ 1][c2 * 8]);
                }
            }
#pragma unroll
            for (int ks = 0; ks < 2; ++ks) {
                u16x8 b[3];
#pragma unroll
                for (int j = 0; j < 3; ++j) {
                    int C = wc * 48 + j * 16 + r15;
                    b[j] = *(const u16x8*)&Bs2[cur][C * 64 + (((ks * 4 + g4) ^ (C & 7)) * 8)];
                }
#pragma unroll
                for (int j = 0; j < 3; ++j)
#pragma unroll
                    for (int i = 0; i < 2; ++i)
                        acc[j][i] = mfma16(b[j], af[i][2 * kt + ks], acc[j][i]);
            }
            if (kt == 3) {
                // epilogue -> qkvh LDS (packed 8B; V 2-way XOR swizzled)
#pragma unroll
                for (int j = 0; j < 3; ++j) {
                    int cp0 = wc * 48 + j * 16 + g4 * 4;       // 0..95
                    float4 bias = *(const float4*)&bq2[hd * 96 + cp0];
                    int mat = cp0 >> 5, e0 = cp0 & 31;
#pragma unroll
                    for (int i = 0; i < 2; ++i) {
                        int point = i * 16 + r15;
                        unsigned lo = pk2(acc[j][i][0] + bias.x, acc[j][i][1] + bias.y);
                        unsigned hi = pk2(acc[j][i][2] + bias.z, acc[j][i][3] + bias.w);
                        int ed = (mat == 2) ? (e0 ^ (((point >> 3) & 1) << 4)) : e0;
                        *(u32x2*)&qkvh[wr][mat][point][ed] = (u32x2){lo, hi};
                        acc[j][i] = (f32x4){0.f, 0.f, 0.f, 0.f};
                    }
                }
            }
            __syncthreads();
        }

        // ---- attention for head hd (k23 math, LDS-sourced) ----
        float sig = sigma[hd];
        u16x8 aq[2], bk[2];
#pragma unroll
        for (int i = 0; i < 2; ++i) {
            aq[i] = *(const u16x8*)&qkvh[wr][0][i * 16 + r15][g4 * 8];
            bk[i] = *(const u16x8*)&qkvh[wr][1][i * 16 + r15][g4 * 8];
        }
        f32x4 s[2][2];
#pragma unroll
        for (int i = 0; i < 2; ++i)
#pragma unroll
            for (int j = 0; j < 2; ++j)
                s[i][j] = mfma16(aq[i], bk[j], (f32x4){0.f, 0.f, 0.f, 0.f});

#pragma unroll
        for (int i = 0; i < 2; ++i) {
#pragma unroll
            for (int r = 0; r < 4; ++r) {
                int row = i * 16 + g4 * 4 + r;
                float v0 = s[i][0][r] * scale + sig * dist_s[wr][row][r15];
                float v1 = s[i][1][r] * scale + sig * dist_s[wr][row][16 + r15];
                float m = fmaxf(v0, v1);
                m = fmaxf(m, __shfl_xor(m, 1));
                m = fmaxf(m, __shfl_xor(m, 2));
                m = fmaxf(m, __shfl_xor(m, 4));
                m = fmaxf(m, __shfl_xor(m, 8));
                float e0 = __expf(v0 - m), e1 = __expf(v1 - m);
                float su = e0 + e1;
                su += __shfl_xor(su, 1);
                su += __shfl_xor(su, 2);
                su += __shfl_xor(su, 4);
                su += __shfl_xor(su, 8);
                float rin = 1.0f / su;
                if (wc == 0) {
                    P_s[wr][row][r15]      = f2bf(e0 * rin);
                    P_s[wr][row][16 + r15] = f2bf(e1 * rin);
                }
            }
        }
        __syncthreads();                      // P_s ready

        u16x8 pa[2];
#pragma unroll
        for (int i = 0; i < 2; ++i)
            pa[i] = *(const u16x8*)&P_s[wr][i * 16 + r15][g4 * 8];
        u16x8 bv;
#pragma unroll
        for (int jj = 0; jj < 8; ++jj) {
            int kp = g4 * 8 + jj;
            int ev = (wc * 16 + r15) ^ (((kp >> 3) & 1) << 4);
            bv[jj] = qkvh[wr][2][kp][ev];
        }
        // swapped PV: C rows = e (in-thread), cols = point (lane)
#pragma unroll
        for (int i = 0; i < 2; ++i) {
            f32x4 o = mfma16(bv, pa[i], (f32x4){0.f, 0.f, 0.f, 0.f});
            int point = i * 16 + r15;
            int e0 = wc * 16 + g4 * 4;
            unsigned lo = pk2(o[0], o[1]);
            unsigned hi = pk2(o[2], o[3]);
            *(u32x2*)&ao[(size_t)(ball_g * 32 + point) * 256 + hd * 32 + e0] = (u32x2){lo, hi};
        }
        __syncthreads();                      // qkvh/P_s free for next head
    }
}

// ---------------- K2: projection (k23 verbatim minus attention) -------------
__global__ __launch_bounds__(256) void k2_proj(const u16* __restrict__ ao,
                                               const u16* __restrict__ wpF,
                                               const float* __restrict__ bp,
                                               float* __restrict__ out) {
    int ball = blockIdx.x, t = threadIdx.x;
    int lane = t & 63, wv = t >> 6;
    int r15 = lane & 15, g4 = lane >> 4;
    const size_t rowb = (size_t)ball * 32;

    f32x4 pacc[4][2];
#pragma unroll
    for (int tt = 0; tt < 4; ++tt)
#pragma unroll
        for (int i = 0; i < 2; ++i) pacc[tt][i] = (f32x4){0.f, 0.f, 0.f, 0.f};
#pragma unroll
    for (int hk = 0; hk < 8; ++hk) {
        u16x8 apj[2];
#pragma unroll
        for (int i = 0; i < 2; ++i)
            apj[i] = *(const u16x8*)&ao[(rowb + i * 16 + r15) * 256 + hk * 32 + g4 * 8];
#pragma unroll
        for (int tt = 0; tt < 4; ++tt) {
            int gct = wv * 4 + tt;
            u16x8 b = *(const u16x8*)&wpF[(size_t)((gct * 8 + hk) * 64 + lane) * 8];
            pacc[tt][0] = mfma16(apj[0], b, pacc[tt][0]);
            pacc[tt][1] = mfma16(apj[1], b, pacc[tt][1]);
        }
    }
#pragma unroll
    for (int tt = 0; tt < 4; ++tt) {
        int ct = (wv * 4 + tt) * 16;
        float bb = bp[ct + r15];
#pragma unroll
        for (int i = 0; i < 2; ++i)
#pragma unroll
            for (int r = 0; r < 4; ++r) {
                size_t row = rowb + i * 16 + g4 * 4 + r;
                out[row * 256 + ct + r15] = pacc[tt][i][r] + bb;
            }
    }
}

extern "C" void kernel_launch(void* const* d_in, const int* in_sizes, int n_in,
                              void* d_out, int out_size, void* d_ws, size_t ws_size,
                              hipStream_t stream) {
    (void)in_sizes; (void)n_in; (void)out_size; (void)ws_size;
    const float* x      = (const float*)d_in[0];
    const float* pos    = (const float*)d_in[1];
    const float* w_qkv  = (const float*)d_in[2];
    const float* b_qkv  = (const float*)d_in[3];
    const float* w_pe   = (const float*)d_in[4];
    const float* b_pe   = (const float*)d_in[5];
    const float* w_proj = (const float*)d_in[6];
    const float* b_proj = (const float*)d_in[7];
    const float* sigma  = (const float*)d_in[8];
    float* out = (float*)d_out;

    u16* ao      = (u16*)d_ws;                      // N*256 bf16 = 134 MB
    u16* wqkvT2  = ao + (size_t)NPTS * 256;         // 768*256 u16
    u16* wpF     = wqkvT2 + 768 * 256;              // 65536 u16
    float* bq2   = (float*)(wpF + 65536);           // 768 f32

    k0_wprep<<<800, 256, 0, stream>>>(w_qkv, b_qkv, w_proj, wqkvT2, wpF, bq2);
    k1_fused<<<2048, 512, 0, stream>>>(x, pos, w_pe, b_pe, wqkvT2, bq2, sigma, ao);
    k2_proj<<<NBALLS, 256, 0, stream>>>(ao, wpF, b_proj, out);
}

// Round 16
// 504.410 us; speedup vs baseline: 1.0317x; 1.0317x over previous
//
#include <hip/hip_runtime.h>

#define NPTS   262144
#define NBALLS 8192
#define MSZ    32

typedef unsigned short u16;
typedef __attribute__((ext_vector_type(8))) unsigned short u16x8;
typedef __attribute__((ext_vector_type(8))) __bf16 bf16x8;
typedef __attribute__((ext_vector_type(4))) float f32x4;
typedef __attribute__((ext_vector_type(2))) unsigned u32x2;

__device__ inline u16 f2bf(float f) {
    unsigned u = __builtin_bit_cast(unsigned, f);
    u += 0x7fffu + ((u >> 16) & 1u);           // RNE
    return (u16)(u >> 16);
}

__device__ inline unsigned pk2(float lo, float hi) {   // lo -> bits 0-15
    return (unsigned)f2bf(lo) | ((unsigned)f2bf(hi) << 16);
}

__device__ inline f32x4 mfma16(u16x8 a, u16x8 b, f32x4 c) {
    return __builtin_amdgcn_mfma_f32_16x16x32_bf16(
        __builtin_bit_cast(bf16x8, a), __builtin_bit_cast(bf16x8, b), c, 0, 0, 0);
}

// ---------------- K0: weight prep — head-major fragment-order wqkvF ----------
// wqkvF[((tile*8+ks)*64+lane)*8+j] = bf16(W[k][cp]), cp = tile*16 + (lane&15)
// head-major: cp = h*96 + mat*32 + e  <->  orig col = h*96 + e*3 + mat
// wpF unchanged (round-7 verified).
__global__ __launch_bounds__(256) void k0_wprep(const float* __restrict__ w_qkv,
                                                const float* __restrict__ b_qkv,
                                                const float* __restrict__ w_proj,
                                                u16* __restrict__ wqkvF,
                                                u16* __restrict__ wpF,
                                                float* __restrict__ bq2) {
    int g = blockIdx.x * 256 + threadIdx.x;     // grid 128 -> 32768 threads
    if (g < 768) {
        int cp = g;
        int h = cp / 96, rem = cp % 96, mat = rem >> 5, e = rem & 31;
        bq2[cp] = b_qkv[h * 96 + e * 3 + mat];
    }
    if (g < 24576) {
        int lane = g & 63, ks = (g >> 6) & 7, tile = g >> 9;    // tile < 48
        int r15 = lane & 15, g4 = lane >> 4;
        int cp = tile * 16 + r15;
        int h = cp / 96, rem = cp % 96, mat = rem >> 5, e = rem & 31;
        int orig = h * 96 + e * 3 + mat;
        int k0 = ks * 32 + g4 * 8;
        u16x8 o;
#pragma unroll
        for (int j = 0; j < 8; ++j)
            o[j] = f2bf(w_qkv[(size_t)(k0 + j) * 768 + orig]);
        *(u16x8*)&wqkvF[(size_t)g * 8] = o;
    } else {
        int tid2 = g - 24576;                   // < 8192
        int lane = tid2 & 63, ch = tid2 >> 6;
        int hk = ch & 7, gct = ch >> 3;
        int r15 = lane & 15, g4 = lane >> 4;
        u16x8 o;
#pragma unroll
        for (int j = 0; j < 8; ++j)
            o[j] = f2bf(w_proj[(size_t)(hk * 32 + g4 * 8 + j) * 256 + gct * 16 + r15]);
        *(u16x8*)&wpF[(size_t)tid2 * 8] = o;
    }
}

// ---------------- K1: fused pos-embed + QKV + attention ---------------------
// 512 thr, 4 balls. Per head: barrier-free GEMM (B-frags from L2-resident
// fragment-order wqkvF) -> qkvh LDS (stride 40) -> attention -> ao.
__global__ __launch_bounds__(512, 4) void k1_fused(const float* __restrict__ x,
                                                   const float* __restrict__ pos,
                                                   const float* __restrict__ w_pe,
                                                   const float* __restrict__ b_pe,
                                                   const u16* __restrict__ wqkvF,
                                                   const float* __restrict__ bq2,
                                                   const float* __restrict__ sigma,
                                                   u16* __restrict__ ao) {
    __shared__ __align__(16) u16 qkvh[4][3][MSZ][40];  // 30 KB (Astage in prologue)
    __shared__ float dist_s[4][MSZ][33];               // 16.9 KB (padded, R14)
    __shared__ __align__(16) char upool[10240];        // prologue tables / P_s

    float* ps_s  = (float*)upool;             // 384
    float* ctr_s = ps_s + 384;                // 12
    float* rel_s = ctr_s + 12;                // 384  rel_s[row*3+d]
    float* wpe_s = rel_s + 384;               // 768  wpe_s[d*256+k]
    float* bpe_s = wpe_s + 768;               // 256
    typedef u16 (*PsT)[MSZ][40];
    PsT P_s = (PsT)upool;                     // P_s[4][32][40] (post-prologue)

    int id = blockIdx.x;
    int rt = (id >> 3) + (id & 7) * 256;      // bijective XCD swizzle (2048%8==0)
    int t = threadIdx.x;
    int lane = t & 63, wv = t >> 6;
    int r15 = lane & 15, g4 = lane >> 4;
    int wr = wv >> 1, wc = wv & 1;            // ball-in-block, col-half
    int rowbase = rt * 128;
    const int ball_g = rt * 4 + wr;
    const float scale = 0.17677669529663687f; // 1/sqrt(32)

    // ---- prologue tables ----
    if (t < 384) ps_s[t] = pos[(size_t)rt * 384 + t];
    if (t < 256) bpe_s[t] = b_pe[t];
    for (int i = t; i < 768; i += 512) wpe_s[i] = w_pe[i];
    __syncthreads();
    if (t < 12) {
        int b = t / 3, m = t % 3;
        float s = 0.f;
#pragma unroll
        for (int j = 0; j < MSZ; ++j) s += ps_s[(b * 32 + j) * 3 + m];
        ctr_s[b * 3 + m] = s * (1.0f / MSZ);
    }
    __syncthreads();
    if (t < 384) {
        int p = t / 3, m = t % 3;
        rel_s[t] = ps_s[t] - ctr_s[(p >> 5) * 3 + m];
    }
    for (int idx2 = t; idx2 < 4096; idx2 += 512) {
        int b = idx2 >> 10, m = (idx2 >> 5) & 31, kk = idx2 & 31;
        float dx = ps_s[(b * 32 + m) * 3 + 0] - ps_s[(b * 32 + kk) * 3 + 0];
        float dy = ps_s[(b * 32 + m) * 3 + 1] - ps_s[(b * 32 + kk) * 3 + 1];
        float dz = ps_s[(b * 32 + m) * 3 + 2] - ps_s[(b * 32 + kk) * 3 + 2];
        dist_s[b][m][kk] = sqrtf(fmaxf(dx * dx + dy * dy + dz * dz, 1e-12f));
    }
    __syncthreads();                          // rel_s + dist ready

    // ---- embed -> register A-frags via qkvh-as-Astage (R14/15 verbatim) ----
    u16* Ast = &qkvh[0][0][0][0];
    u16x8 af[2][8];
#pragma unroll
    for (int kt = 0; kt < 4; ++kt) {
#pragma unroll
        for (int i = 0; i < 2; ++i) {
            int c = i * 512 + t;
            int row = c >> 3, g = c & 7;
            int kk0 = kt * 64 + g * 8;
            float4 xa = *(const float4*)&x[(size_t)(rowbase + row) * 256 + kk0];
            float4 xb = *(const float4*)&x[(size_t)(rowbase + row) * 256 + kk0 + 4];
            float r0 = rel_s[row * 3 + 0], r1 = rel_s[row * 3 + 1], r2 = rel_s[row * 3 + 2];
            u16x8 o;
#pragma unroll
            for (int m = 0; m < 8; ++m) {
                float xv = (m < 4) ? ((const float*)&xa)[m] : ((const float*)&xb)[m - 4];
                float v = fmaf(r0, wpe_s[0 * 256 + kk0 + m],
                          fmaf(r1, wpe_s[1 * 256 + kk0 + m],
                          fmaf(r2, wpe_s[2 * 256 + kk0 + m], xv))) + bpe_s[kk0 + m];
                o[m] = f2bf(v);
            }
            *(u16x8*)&Ast[(row * 8 + (g ^ (row & 7))) * 8] = o;
        }
        __syncthreads();
#pragma unroll
        for (int ks = 0; ks < 2; ++ks)
#pragma unroll
            for (int i = 0; i < 2; ++i) {
                int R = wr * 32 + i * 16 + r15;
                af[i][2 * kt + ks] =
                    *(const u16x8*)&Ast[R * 64 + (((ks * 4 + g4) ^ (R & 7)) * 8)];
            }
        __syncthreads();
    }

    // ---- main loop: 8 heads; barrier-free GEMM, 3 barriers/head ------------
    for (int hd = 0; hd < 8; ++hd) {
        f32x4 acc[3][2];
#pragma unroll
        for (int j = 0; j < 3; ++j)
#pragma unroll
            for (int i = 0; i < 2; ++i) acc[j][i] = (f32x4){0.f, 0.f, 0.f, 0.f};

        // GEMM: B-frags coalesced from L2-resident wqkvF (R10-verified pattern)
#pragma unroll
        for (int ks = 0; ks < 8; ++ks) {
            u16x8 b[3];
#pragma unroll
            for (int j = 0; j < 3; ++j) {
                int tile = hd * 6 + wc * 3 + j;
                b[j] = *(const u16x8*)&wqkvF[(size_t)((tile * 8 + ks) * 64 + lane) * 8];
            }
#pragma unroll
            for (int j = 0; j < 3; ++j)
#pragma unroll
                for (int i = 0; i < 2; ++i)
                    acc[j][i] = mfma16(b[j], af[i][ks], acc[j][i]);
        }
        // epilogue -> qkvh LDS (stride 40; V 2-way XOR swizzled — R15 pair)
#pragma unroll
        for (int j = 0; j < 3; ++j) {
            int cp0 = wc * 48 + j * 16 + g4 * 4;       // 0..95
            float4 bias = *(const float4*)&bq2[hd * 96 + cp0];
            int mat = cp0 >> 5, e0 = cp0 & 31;
#pragma unroll
            for (int i = 0; i < 2; ++i) {
                int point = i * 16 + r15;
                unsigned lo = pk2(acc[j][i][0] + bias.x, acc[j][i][1] + bias.y);
                unsigned hi = pk2(acc[j][i][2] + bias.z, acc[j][i][3] + bias.w);
                int ed = (mat == 2) ? (e0 ^ (((point >> 3) & 1) << 4)) : e0;
                *(u32x2*)&qkvh[wr][mat][point][ed] = (u32x2){lo, hi};
            }
        }
        __syncthreads();                      // (1) qkvh ready

        // ---- attention for head hd (R15-verified math, stride-40 reads) ----
        float sig = sigma[hd];
        u16x8 aq[2], bk[2];
#pragma unroll
        for (int i = 0; i < 2; ++i) {
            aq[i] = *(const u16x8*)&qkvh[wr][0][i * 16 + r15][g4 * 8];
            bk[i] = *(const u16x8*)&qkvh[wr][1][i * 16 + r15][g4 * 8];
        }
        f32x4 s[2][2];
#pragma unroll
        for (int i = 0; i < 2; ++i)
#pragma unroll
            for (int j = 0; j < 2; ++j)
                s[i][j] = mfma16(aq[i], bk[j], (f32x4){0.f, 0.f, 0.f, 0.f});

#pragma unroll
        for (int i = 0; i < 2; ++i) {
#pragma unroll
            for (int r = 0; r < 4; ++r) {
                int row = i * 16 + g4 * 4 + r;
                float v0 = s[i][0][r] * scale + sig * dist_s[wr][row][r15];
                float v1 = s[i][1][r] * scale + sig * dist_s[wr][row][16 + r15];
                float m = fmaxf(v0, v1);
                m = fmaxf(m, __shfl_xor(m, 1));
                m = fmaxf(m, __shfl_xor(m, 2));
                m = fmaxf(m, __shfl_xor(m, 4));
                m = fmaxf(m, __shfl_xor(m, 8));
                float e0 = __expf(v0 - m), e1 = __expf(v1 - m);
                float su = e0 + e1;
                su += __shfl_xor(su, 1);
                su += __shfl_xor(su, 2);
                su += __shfl_xor(su, 4);
                su += __shfl_xor(su, 8);
                float rin = 1.0f / su;
                if (wc == 0) {
                    P_s[wr][row][r15]      = f2bf(e0 * rin);
                    P_s[wr][row][16 + r15] = f2bf(e1 * rin);
                }
            }
        }
        __syncthreads();                      // (2) P_s ready

        u16x8 pa[2];
#pragma unroll
        for (int i = 0; i < 2; ++i)
            pa[i] = *(const u16x8*)&P_s[wr][i * 16 + r15][g4 * 8];
        u16x8 bv;
#pragma unroll
        for (int jj = 0; jj < 8; ++jj) {
            int kp = g4 * 8 + jj;
            int ev = (wc * 16 + r15) ^ (((kp >> 3) & 1) << 4);
            bv[jj] = qkvh[wr][2][kp][ev];
        }
        // swapped PV: C rows = e (in-thread), cols = point (lane)
#pragma unroll
        for (int i = 0; i < 2; ++i) {
            f32x4 o = mfma16(bv, pa[i], (f32x4){0.f, 0.f, 0.f, 0.f});
            int point = i * 16 + r15;
            int e0 = wc * 16 + g4 * 4;
            unsigned lo = pk2(o[0], o[1]);
            unsigned hi = pk2(o[2], o[3]);
            *(u32x2*)&ao[(size_t)(ball_g * 32 + point) * 256 + hd * 32 + e0] = (u32x2){lo, hi};
        }
        __syncthreads();                      // (3) qkvh/P_s free for next head
    }
}

// ---------------- K2: projection (R15 verbatim, verified) -------------------
__global__ __launch_bounds__(256) void k2_proj(const u16* __restrict__ ao,
                                               const u16* __restrict__ wpF,
                                               const float* __restrict__ bp,
                                               float* __restrict__ out) {
    int ball = blockIdx.x, t = threadIdx.x;
    int lane = t & 63, wv = t >> 6;
    int r15 = lane & 15, g4 = lane >> 4;
    const size_t rowb = (size_t)ball * 32;

    f32x4 pacc[4][2];
#pragma unroll
    for (int tt = 0; tt < 4; ++tt)
#pragma unroll
        for (int i = 0; i < 2; ++i) pacc[tt][i] = (f32x4){0.f, 0.f, 0.f, 0.f};
#pragma unroll
    for (int hk = 0; hk < 8; ++hk) {
        u16x8 apj[2];
#pragma unroll
        for (int i = 0; i < 2; ++i)
            apj[i] = *(const u16x8*)&ao[(rowb + i * 16 + r15) * 256 + hk * 32 + g4 * 8];
#pragma unroll
        for (int tt = 0; tt < 4; ++tt) {
            int gct = wv * 4 + tt;
            u16x8 b = *(const u16x8*)&wpF[(size_t)((gct * 8 + hk) * 64 + lane) * 8];
            pacc[tt][0] = mfma16(apj[0], b, pacc[tt][0]);
            pacc[tt][1] = mfma16(apj[1], b, pacc[tt][1]);
        }
    }
#pragma unroll
    for (int tt = 0; tt < 4; ++tt) {
        int ct = (wv * 4 + tt) * 16;
        float bb = bp[ct + r15];
#pragma unroll
        for (int i = 0; i < 2; ++i)
#pragma unroll
            for (int r = 0; r < 4; ++r) {
                size_t row = rowb + i * 16 + g4 * 4 + r;
                out[row * 256 + ct + r15] = pacc[tt][i][r] + bb;
            }
    }
}

extern "C" void kernel_launch(void* const* d_in, const int* in_sizes, int n_in,
                              void* d_out, int out_size, void* d_ws, size_t ws_size,
                              hipStream_t stream) {
    (void)in_sizes; (void)n_in; (void)out_size; (void)ws_size;
    const float* x      = (const float*)d_in[0];
    const float* pos    = (const float*)d_in[1];
    const float* w_qkv  = (const float*)d_in[2];
    const float* b_qkv  = (const float*)d_in[3];
    const float* w_pe   = (const float*)d_in[4];
    const float* b_pe   = (const float*)d_in[5];
    const float* w_proj = (const float*)d_in[6];
    const float* b_proj = (const float*)d_in[7];
    const float* sigma  = (const float*)d_in[8];
    float* out = (float*)d_out;

    u16* ao     = (u16*)d_ws;                       // N*256 bf16 = 134 MB
    u16* wqkvF  = ao + (size_t)NPTS * 256;          // 196608 u16
    u16* wpF    = wqkvF + 196608;                   // 65536 u16
    float* bq2  = (float*)(wpF + 65536);            // 768 f32

    k0_wprep<<<128, 256, 0, stream>>>(w_qkv, b_qkv, w_proj, wqkvF, wpF, bq2);
    k1_fused<<<2048, 512, 0, stream>>>(x, pos, w_pe, b_pe, wqkvF, bq2, sigma, ao);
    k2_proj<<<NBALLS, 256, 0, stream>>>(ao, wpF, b_proj, out);
}